// Round 1
// 408.895 us; speedup vs baseline: 1.0371x; 1.0371x over previous
//
#include <hip/hip_runtime.h>
#include <float.h>
#include <math.h>

// Problem constants
#define B_    256
#define N_    197
#define C_    768
#define POOL_ 1024
#define LEN_  8
#define TOPK_ 8
#define PROWS (POOL_*LEN_)          // 8192 projected pool rows
#define OUTROWS 261                 // 1 + 64 + 196

typedef __attribute__((ext_vector_type(8))) short short8_t;
typedef __attribute__((ext_vector_type(4))) float f32x4;

// ---------------- workspace layout (byte offsets, all 256-aligned) ----------
static const size_t OFF_XMEAN = 0;          //  256*768*4  =   786432
static const size_t OFF_XNORM = 786432;     //  256*768*4  =   786432
static const size_t OFF_PNORM = 1572864;    // 1024*768*4  =  3145728
static const size_t OFF_SIM   = 4718592;    // 256*1024*4  =  1048576
static const size_t OFF_IDX   = 5767168;    // 256*8*4     =     8192
static const size_t OFF_ACC   = 5775360;    // scalar pad  =      256
static const size_t OFF_ABF   = 5775616;    // 8192*768*2  = 12582912
static const size_t OFF_WBF   = 18358528;   //  768*768*2  =  1179648
static const size_t OFF_PROJ  = 19538176;   // 8192*768*4  = 25165824
// total ~44.7 MB

// ---------------- K1: fused mean-pool + concat copy -------------------------
// grid = B*3 blocks of 256 threads; 4 waves stream 4 consecutive rows/iter.
// Block (b,seg) owns 64 float4 columns. Nontemporal on the stream-once path
// (x read once; out rows never re-read) to keep L2/L3 for K5/K6 working set.
__global__ __launch_bounds__(256) void k1_mean_copy(const float* __restrict__ x,
                                                    float* __restrict__ out,
                                                    float* __restrict__ xmean) {
    int b   = blockIdx.x / 3;
    int seg = blockIdx.x % 3;
    int t = threadIdx.x;
    int r = t >> 6;                         // wave id 0..3 = row offset
    int c = t & 63;
    int c4 = seg * 64 + c;                  // float4 column 0..191
    const f32x4* xin  = (const f32x4*)x   + (size_t)b * (N_ * 192) + c4;
    f32x4*       outb = (f32x4*)out       + (size_t)b * (OUTROWS * 192) + c4;

    float sx = 0.f, sy = 0.f, sz = 0.f, sw = 0.f;
    // rows r, r+4, ..., covers n=0..195
    #pragma unroll 7
    for (int n = r; n < 196; n += 4) {
        f32x4 v = __builtin_nontemporal_load(&xin[(size_t)n * 192]);
        sx += v.x; sy += v.y; sz += v.z; sw += v.w;
        int orow = (n == 0) ? 0 : (64 + n);
        __builtin_nontemporal_store(v, &outb[(size_t)orow * 192]);
    }
    if (r == 0) {                           // row 196 remainder
        f32x4 v = __builtin_nontemporal_load(&xin[(size_t)196 * 192]);
        sx += v.x; sy += v.y; sz += v.z; sw += v.w;
        __builtin_nontemporal_store(v, &outb[(size_t)260 * 192]);
    }
    __shared__ f32x4 red[4][64];
    f32x4 s; s.x = sx; s.y = sy; s.z = sz; s.w = sw;
    red[r][c] = s;
    __syncthreads();
    if (r == 0) {
        f32x4 a = red[0][c], b2 = red[1][c], c2 = red[2][c], d = red[3][c];
        const float inv = 1.0f / (float)N_;
        f32x4 m;
        m.x = (a.x + b2.x + c2.x + d.x) * inv;
        m.y = (a.y + b2.y + c2.y + d.y) * inv;
        m.z = (a.z + b2.z + c2.z + d.z) * inv;
        m.w = (a.w + b2.w + c2.w + d.w) * inv;
        ((f32x4*)xmean)[b * 192 + c4] = m;
    }
}

// ---------------- K2 (fused): L2-normalize rows + fp32->bf16 conversions ----
// Blocks [0, B+POOL): normalize x_mean / prompt_key rows (identical math to
// the previous passing version -> bit-exact sim -> stable top-k).
// Blocks [B+POOL, +6720): convert prompt + proj_w to bf16 (independent work,
// fused to save a launch).
__device__ __forceinline__ unsigned short f2bf(float f) {
    unsigned int u = __float_as_uint(f);
    u += 0x7fffu + ((u >> 16) & 1u);              // round-to-nearest-even
    return (unsigned short)(u >> 16);
}
__global__ __launch_bounds__(256) void k2_norm_convert(const float* __restrict__ xmean,
                                                       const float* __restrict__ pkey,
                                                       float* __restrict__ xnorm,
                                                       float* __restrict__ pnorm,
                                                       float* __restrict__ sim_accum,
                                                       const float* __restrict__ prompt,
                                                       const float* __restrict__ projw,
                                                       unsigned short* __restrict__ Abf,
                                                       unsigned short* __restrict__ Wbf) {
    int r = blockIdx.x;
    int t = threadIdx.x;
    if (r < B_ + POOL_) {
        __shared__ float red[256];
        const float* src; float* dst;
        if (r < B_) { src = xmean + (size_t)r * C_; dst = xnorm + (size_t)r * C_; }
        else        { src = pkey  + (size_t)(r - B_) * C_; dst = pnorm + (size_t)(r - B_) * C_; }
        float v0 = src[t], v1 = src[t + 256], v2 = src[t + 512];
        red[t] = v0*v0 + v1*v1 + v2*v2;
        __syncthreads();
        for (int off = 128; off > 0; off >>= 1) {
            if (t < off) red[t] += red[t + off];
            __syncthreads();
        }
        float inv = 1.0f / sqrtf(fmaxf(red[0], 1e-12f));
        dst[t] = v0 * inv; dst[t + 256] = v1 * inv; dst[t + 512] = v2 * inv;
        if (r == 0 && t == 0) sim_accum[0] = 0.0f;   // zero accumulator (ws is poisoned)
    } else {
        int i4 = (r - (B_ + POOL_)) * 256 + t;        // 0 .. 1720319
        float4 v; unsigned short* d;
        if (i4 < (PROWS * C_ / 4)) {
            v = ((const float4*)prompt)[i4];
            d = Abf + (size_t)i4 * 4;
        } else {
            int j4 = i4 - PROWS * C_ / 4;
            v = ((const float4*)projw)[j4];
            d = Wbf + (size_t)j4 * 4;
        }
        ushort4 o; o.x = f2bf(v.x); o.y = f2bf(v.y); o.z = f2bf(v.z); o.w = f2bf(v.w);
        *(ushort4*)d = o;
    }
}

// ---------------- K3: fp32 similarity GEMM  sim = xnorm @ pnorm^T -----------
// M=256, N=1024, K=768.  32x32 tiles, grid (32 n-tiles, 8 m-tiles), 256 thr.
// v2: float4 LDS reads (4x fewer ds instrs; pad 36 keeps 16B alignment) and
// register prefetch of the next k-tile overlapped with compute.
// FMA accumulation order per accumulator is IDENTICAL to v1 (bit-exact sim).
__global__ __launch_bounds__(256) void k3_sim(const float* __restrict__ xnorm,
                                              const float* __restrict__ pnorm,
                                              float* __restrict__ sim) {
    __shared__ float As[32][36];
    __shared__ float Bs[32][36];
    int t = threadIdx.x;
    int m0 = blockIdx.y * 32, n0 = blockIdx.x * 32;
    int lrow = t >> 3, lc = (t & 7) * 4;
    int ty = t >> 4, tx = t & 15;
    float a00 = 0.f, a01 = 0.f, a10 = 0.f, a11 = 0.f;
    float4 va = *(const float4*)&xnorm[(size_t)(m0 + lrow) * C_ + lc];
    float4 vb = *(const float4*)&pnorm[(size_t)(n0 + lrow) * C_ + lc];
    for (int k0 = 0; k0 < C_; k0 += 32) {
        __syncthreads();
        *(float4*)&As[lrow][lc] = va;
        *(float4*)&Bs[lrow][lc] = vb;
        __syncthreads();
        if (k0 + 32 < C_) {                 // prefetch next tile during compute
            va = *(const float4*)&xnorm[(size_t)(m0 + lrow) * C_ + k0 + 32 + lc];
            vb = *(const float4*)&pnorm[(size_t)(n0 + lrow) * C_ + k0 + 32 + lc];
        }
        #pragma unroll
        for (int kk = 0; kk < 32; kk += 4) {
            float4 A0 = *(const float4*)&As[ty*2][kk];
            float4 A1 = *(const float4*)&As[ty*2+1][kk];
            float4 B0 = *(const float4*)&Bs[tx*2][kk];
            float4 B1 = *(const float4*)&Bs[tx*2+1][kk];
            a00 += A0.x*B0.x; a00 += A0.y*B0.y; a00 += A0.z*B0.z; a00 += A0.w*B0.w;
            a01 += A0.x*B1.x; a01 += A0.y*B1.y; a01 += A0.z*B1.z; a01 += A0.w*B1.w;
            a10 += A1.x*B0.x; a10 += A1.y*B0.y; a10 += A1.z*B0.z; a10 += A1.w*B0.w;
            a11 += A1.x*B1.x; a11 += A1.y*B1.y; a11 += A1.z*B1.z; a11 += A1.w*B1.w;
        }
    }
    sim[(size_t)(m0 + ty*2    ) * POOL_ + n0 + tx*2    ] = a00;
    sim[(size_t)(m0 + ty*2    ) * POOL_ + n0 + tx*2 + 1] = a01;
    sim[(size_t)(m0 + ty*2 + 1) * POOL_ + n0 + tx*2    ] = a10;
    sim[(size_t)(m0 + ty*2 + 1) * POOL_ + n0 + tx*2 + 1] = a11;
}

// ---------------- K4: top-8 per row (lax.top_k semantics) -------------------
__global__ __launch_bounds__(256) void k4_topk(const float* __restrict__ sim,
                                               int* __restrict__ idx,
                                               float* __restrict__ sim_accum) {
    __shared__ float vals[POOL_];
    __shared__ float wv[4];
    __shared__ int   wi[4];
    int b = blockIdx.x, t = threadIdx.x;
    int wave = t >> 6;
    #pragma unroll
    for (int i = 0; i < 4; ++i) vals[t + 256*i] = sim[(size_t)b * POOL_ + t + 256*i];
    __syncthreads();
    float sumv = 0.0f;
    for (int k = 0; k < TOPK_; ++k) {
        float bv = -FLT_MAX; int bi = POOL_;
        #pragma unroll
        for (int i = 0; i < 4; ++i) {          // ascending n -> ties keep lower idx
            int n = t + 256*i;
            float v = vals[n];
            if (v > bv) { bv = v; bi = n; }
        }
        #pragma unroll
        for (int off = 32; off > 0; off >>= 1) {
            float v2 = __shfl_down(bv, off);
            int   i2 = __shfl_down(bi, off);
            if (v2 > bv || (v2 == bv && i2 < bi)) { bv = v2; bi = i2; }
        }
        if ((t & 63) == 0) { wv[wave] = bv; wi[wave] = bi; }
        __syncthreads();
        if (t == 0) {
            float fv = wv[0]; int fi = wi[0];
            #pragma unroll
            for (int w = 1; w < 4; ++w) {
                float v2 = wv[w]; int i2 = wi[w];
                if (v2 > fv || (v2 == fv && i2 < fi)) { fv = v2; fi = i2; }
            }
            idx[b*TOPK_ + k] = fi;
            sumv += fv;
            vals[fi] = -FLT_MAX;
        }
        __syncthreads();
    }
    if (t == 0) atomicAdd(sim_accum, sumv);
}

// ---------------- K5: bf16 MFMA projection GEMM over the whole pool ---------
// proj_all[8192,768] = A(bf16) @ W(bf16)^T + bias + prompt(fp32)
// v2: T3-minimum 2-phase double-buffered pipeline -- issue next K-tile's
// global_load_lds BEFORE computing the current tile; ONE barrier per K-step
// (was 2). LDS 2x12KB = 24KB, still 3 blocks/CU at grid 768.
__global__ __launch_bounds__(256) void k5_gemm(const unsigned short* __restrict__ A,
                                               const unsigned short* __restrict__ W,
                                               const float* __restrict__ bias,
                                               const float* __restrict__ resid,
                                               float* __restrict__ out) {
    __shared__ short As[2][64*32];
    __shared__ short Bs[2][128*32];
    const int tid = threadIdx.x;
    const int m0 = blockIdx.y * 64, n0 = blockIdx.x * 128;
    const int wave = tid >> 6, lane = tid & 63;
    const int quad = lane >> 4, lr = lane & 15;
    const int srow = tid >> 2;              // 0..63
    const int scol = (tid & 3) * 8;         // 0,8,16,24

    f32x4 acc[4][2] = {};

    auto stage = [&](int buf, int kt) {
        const int k0 = kt * 32;
        __builtin_amdgcn_global_load_lds(
            (const __attribute__((address_space(1))) void*)&A[(size_t)(m0 + srow) * C_ + k0 + scol],
            (__attribute__((address_space(3))) void*)&As[buf][srow*32 + scol], 16, 0, 0);
        __builtin_amdgcn_global_load_lds(
            (const __attribute__((address_space(1))) void*)&W[(size_t)(n0 + srow) * C_ + k0 + scol],
            (__attribute__((address_space(3))) void*)&Bs[buf][srow*32 + scol], 16, 0, 0);
        __builtin_amdgcn_global_load_lds(
            (const __attribute__((address_space(1))) void*)&W[(size_t)(n0 + 64 + srow) * C_ + k0 + scol],
            (__attribute__((address_space(3))) void*)&Bs[buf][(64 + srow)*32 + scol], 16, 0, 0);
    };
    auto compute = [&](int buf) {
        short8_t af[4], bf[2];
        #pragma unroll
        for (int i = 0; i < 4; ++i)
            af[i] = *(const short8_t*)&As[buf][(i*16 + lr)*32 + quad*8];
        #pragma unroll
        for (int j = 0; j < 2; ++j)
            bf[j] = *(const short8_t*)&Bs[buf][(wave*32 + j*16 + lr)*32 + quad*8];
        #pragma unroll
        for (int i = 0; i < 4; ++i)
            #pragma unroll
            for (int j = 0; j < 2; ++j)
                acc[i][j] = __builtin_amdgcn_mfma_f32_16x16x32_bf16(af[i], bf[j], acc[i][j], 0, 0, 0);
    };

    stage(0, 0);
    __syncthreads();                        // compiler drains vmcnt before barrier
    int cur = 0;
    for (int kt = 0; kt < 23; ++kt) {
        stage(cur ^ 1, kt + 1);             // overlap next stage with this compute
        compute(cur);
        __syncthreads();                    // next-tile staged AND this tile's reads done
        cur ^= 1;
    }
    compute(cur);                           // last tile, no prefetch

    // epilogue: + bias[n] + fp32 residual, store fp32
    #pragma unroll
    for (int j = 0; j < 2; ++j) {
        const int n = n0 + wave*32 + j*16 + lr;
        const float bn = bias[n];
        #pragma unroll
        for (int i = 0; i < 4; ++i) {
            const int mbase = m0 + i*16 + quad*4;
            #pragma unroll
            for (int r = 0; r < 4; ++r) {
                const int m = mbase + r;
                out[(size_t)m * C_ + n] = acc[i][j][r] + bn + resid[(size_t)m * C_ + n];
            }
        }
    }
}

// ---------------- K6: gather projected rows into output + scalar ------------
// v2: 256-thread blocks (4 rows each, 4096 blocks) + nontemporal out stores.
__global__ __launch_bounds__(256) void k6_gather(const float* __restrict__ projall,
                                                 const int* __restrict__ idx,
                                                 const float* __restrict__ sim_accum,
                                                 float* __restrict__ out) {
    int row = blockIdx.x * 4 + (threadIdx.x >> 6);   // 0..16383 = (b, j)
    int t = threadIdx.x & 63;
    int b = row >> 6, j = row & 63;
    int k = j >> 3, l = j & 7;
    int p = idx[b * TOPK_ + k];
    const f32x4* src = (const f32x4*)projall + (size_t)(p * LEN_ + l) * 192;
    f32x4* dst = (f32x4*)out + (size_t)(b * OUTROWS + 1 + j) * 192;
    __builtin_nontemporal_store(src[t],       &dst[t]);
    __builtin_nontemporal_store(src[t + 64],  &dst[t + 64]);
    __builtin_nontemporal_store(src[t + 128], &dst[t + 128]);
    if (row == 0 && t == 0)
        out[(size_t)B_ * OUTROWS * C_] = sim_accum[0] * (1.0f / (float)B_);
}

// ---------------- launcher ---------------------------------------------------
extern "C" void kernel_launch(void* const* d_in, const int* in_sizes, int n_in,
                              void* d_out, int out_size, void* d_ws, size_t ws_size,
                              hipStream_t stream) {
    const float* x_embed = (const float*)d_in[0];
    const float* prompt  = (const float*)d_in[1];
    const float* pkey    = (const float*)d_in[2];
    const float* projw   = (const float*)d_in[3];
    const float* projb   = (const float*)d_in[4];
    float* out = (float*)d_out;
    char* ws = (char*)d_ws;

    float*          xmean   = (float*)(ws + OFF_XMEAN);
    float*          xnorm   = (float*)(ws + OFF_XNORM);
    float*          pnorm   = (float*)(ws + OFF_PNORM);
    float*          sim     = (float*)(ws + OFF_SIM);
    int*            idxp    = (int*)(ws + OFF_IDX);
    float*          acc     = (float*)(ws + OFF_ACC);
    unsigned short* Abf     = (unsigned short*)(ws + OFF_ABF);
    unsigned short* Wbf     = (unsigned short*)(ws + OFF_WBF);
    float*          projall = (float*)(ws + OFF_PROJ);

    const int convBlocks = (PROWS * C_ / 4 + 768 * 768 / 4) / 256;   // 6720
    k1_mean_copy<<<B_ * 3, 256, 0, stream>>>(x_embed, out, xmean);
    k2_norm_convert<<<B_ + POOL_ + convBlocks, 256, 0, stream>>>(xmean, pkey, xnorm, pnorm, acc,
                                                                 prompt, projw, Abf, Wbf);
    k3_sim<<<dim3(POOL_ / 32, B_ / 32), 256, 0, stream>>>(xnorm, pnorm, sim);
    k4_topk<<<B_, 256, 0, stream>>>(sim, idxp, acc);
    k5_gemm<<<dim3(C_ / 128, PROWS / 64), 256, 0, stream>>>(Abf, Wbf, projb, prompt, projall);
    k6_gather<<<B_ * 64 / 4, 256, 0, stream>>>(projall, idxp, acc, out);
}